// Round 2
// baseline (904.765 us; speedup 1.0000x reference)
//
#include <hip/hip_runtime.h>
#include <hip/hip_bf16.h>

// Problem constants
constexpr int B_  = 8;
constexpr int L_  = 1024;
constexpr int D_  = 768;
constexpr int H_  = 12;
constexpr int DK_ = 64;
constexpr int SD_ = 5;
constexpr int VALID_ = 768;   // keys t >= 768 are masked

// 0.125 (1/sqrt(64)) * log2(e): exp(0.125*s) = exp2(SSCALE*s)
constexpr float SSCALE_ = 0.18033688011112042f;

typedef __attribute__((ext_vector_type(8))) __bf16 bf16x8;
typedef __attribute__((ext_vector_type(4))) float floatx4;

__device__ __forceinline__ unsigned short f2bf(float f) {
    unsigned int u = __float_as_uint(f);
    unsigned int r = (u + 0x7FFFu + ((u >> 16) & 1u)) >> 16;  // RNE
    return (unsigned short)r;
}

// async global->LDS, 16B per lane. LDS dest must be linear in lane id.
__device__ __forceinline__ void g2l16(const void* g, void* l) {
    __builtin_amdgcn_global_load_lds(
        (const __attribute__((address_space(1))) void*)g,
        (__attribute__((address_space(3))) void*)l, 16, 0, 0);
}

// ---------------------------------------------------------------------------
// f32 -> bf16 elementwise (8 elems/thread), 3 tensors in one launch
// ---------------------------------------------------------------------------
__global__ __launch_bounds__(256) void cvt3_kernel(
    const float* __restrict__ x0, const float* __restrict__ x1,
    const float* __restrict__ x2,
    unsigned short* __restrict__ o0, unsigned short* __restrict__ o1,
    unsigned short* __restrict__ o2)
{
    const int w = blockIdx.y;
    const float* x = (w == 0) ? x0 : (w == 1) ? x1 : x2;
    unsigned short* o = (w == 0) ? o0 : (w == 1) ? o1 : o2;
    size_t i = ((size_t)blockIdx.x * 256 + threadIdx.x) * 8;
    float4 a = *(const float4*)(x + i);
    float4 b = *(const float4*)(x + i + 4);
    ushort4 q1; q1.x = f2bf(a.x); q1.y = f2bf(a.y); q1.z = f2bf(a.z); q1.w = f2bf(a.w);
    ushort4 q2; q2.x = f2bf(b.x); q2.y = f2bf(b.y); q2.z = f2bf(b.z); q2.w = f2bf(b.w);
    *(ushort4*)(o + i) = q1;
    *(ushort4*)(o + i + 4) = q2;
}

// ---------------------------------------------------------------------------
// W [768k][768n] f32 -> Wt [n][k] bf16 (transpose + convert), 64x64 tiles
// 4 weight matrices in one launch (blockIdx.z)
// ---------------------------------------------------------------------------
__global__ __launch_bounds__(256) void wt4_kernel(
    const float* __restrict__ W0, const float* __restrict__ W1,
    const float* __restrict__ W2, const float* __restrict__ W3,
    unsigned short* __restrict__ T0, unsigned short* __restrict__ T1,
    unsigned short* __restrict__ T2, unsigned short* __restrict__ T3)
{
    const int w = blockIdx.z;
    const float* W = (w == 0) ? W0 : (w == 1) ? W1 : (w == 2) ? W2 : W3;
    unsigned short* Wt = (w == 0) ? T0 : (w == 1) ? T1 : (w == 2) ? T2 : T3;
    __shared__ float tl[64][65];
    const int k0 = blockIdx.x * 64, n0 = blockIdx.y * 64;
    const int tid = threadIdx.x;
    #pragma unroll
    for (int i = 0; i < 4; i++) {
        int c = tid + i * 256;
        int r = c >> 4, c4 = (c & 15) * 4;
        float4 v = *(const float4*)(W + (size_t)(k0 + r) * D_ + n0 + c4);
        tl[r][c4] = v.x; tl[r][c4 + 1] = v.y; tl[r][c4 + 2] = v.z; tl[r][c4 + 3] = v.w;
    }
    __syncthreads();
    #pragma unroll
    for (int i = 0; i < 4; i++) {
        int c = tid + i * 256;
        int n_ = c >> 4, k4 = (c & 15) * 4;
        ushort4 o;
        o.x = f2bf(tl[k4 + 0][n_]); o.y = f2bf(tl[k4 + 1][n_]);
        o.z = f2bf(tl[k4 + 2][n_]); o.w = f2bf(tl[k4 + 3][n_]);
        *(ushort4*)(Wt + (size_t)(n0 + n_) * D_ + k0 + k4) = o;
    }
}

// ---------------------------------------------------------------------------
// Vh [hb][t][dk] bf16 -> Vt [hb][dk][t<768] bf16
// ---------------------------------------------------------------------------
__global__ __launch_bounds__(256) void vt_kernel(
    const unsigned short* __restrict__ Vh, unsigned short* __restrict__ Vt)
{
    __shared__ unsigned short tl[64][65];
    const int t0 = blockIdx.x * 64, hb = blockIdx.y;
    const int tid = threadIdx.x;
    const unsigned short* src = Vh + (size_t)hb * L_ * DK_ + (size_t)t0 * DK_;
    #pragma unroll
    for (int i = 0; i < 4; i++) {
        int c = tid + i * 256;
        int r = c >> 4, c4 = (c & 15) * 4;
        ushort4 v = *(const ushort4*)(src + r * DK_ + c4);
        tl[r][c4] = v.x; tl[r][c4 + 1] = v.y; tl[r][c4 + 2] = v.z; tl[r][c4 + 3] = v.w;
    }
    __syncthreads();
    unsigned short* dst = Vt + (size_t)hb * DK_ * VALID_ + t0;
    #pragma unroll
    for (int i = 0; i < 4; i++) {
        int c = tid + i * 256;
        int dk = c >> 4, t4 = (c & 15) * 4;
        ushort4 o;
        o.x = tl[t4 + 0][dk]; o.y = tl[t4 + 1][dk];
        o.z = tl[t4 + 2][dk]; o.w = tl[t4 + 3][dk];
        *(ushort4*)(dst + (size_t)dk * VALID_ + t4) = o;
    }
}

// ---------------------------------------------------------------------------
// MFMA GEMM, 128x128 tile, BK=32: out bf16 head-major [h][b][l][dk], +bias
// XCD-pinned m-panels: blocks sharing an A panel land on one XCD.
// ---------------------------------------------------------------------------
__global__ __launch_bounds__(256) void gemm_proj3(
    const unsigned short* __restrict__ A0, const unsigned short* __restrict__ A1,
    const unsigned short* __restrict__ A2,
    const unsigned short* __restrict__ B0, const unsigned short* __restrict__ B1,
    const unsigned short* __restrict__ B2,
    const float* __restrict__ bias0, const float* __restrict__ bias1,
    const float* __restrict__ bias2,
    unsigned short* __restrict__ O0, unsigned short* __restrict__ O1,
    unsigned short* __restrict__ O2)
{
    const int which = blockIdx.z;
    const unsigned short* Abf = (which == 0) ? A0 : (which == 1) ? A1 : A2;
    const unsigned short* Bt  = (which == 0) ? B0 : (which == 1) ? B1 : B2;
    const float* bias         = (which == 0) ? bias0 : (which == 1) ? bias1 : bias2;
    unsigned short* out       = (which == 0) ? O0 : (which == 1) ? O1 : O2;

    __shared__ __align__(16) __bf16 As[128 * 32];
    __shared__ __align__(16) __bf16 Bs[128 * 32];
    const int tid = threadIdx.x;
    // XCD swizzle: f%8 ~ XCD; each XCD owns 8 consecutive m-panels
    const int f = blockIdx.x + 6 * blockIdx.y;
    const int xcd = f & 7, j5 = f >> 3;            // j5 in [0,48)
    const int n0 = (j5 % 6) * 128;
    const int m0 = (xcd * 8 + j5 / 6) * 128;
    const int lane = tid & 63, wv = tid >> 6;
    const int quad = lane >> 4, ln15 = lane & 15;
    const int wm = (wv >> 1) * 64, wn = (wv & 1) * 64;
    const __bf16* Ap = (const __bf16*)Abf + (size_t)m0 * D_;
    const __bf16* Bp = (const __bf16*)Bt + (size_t)n0 * D_;
    floatx4 acc[4][4];
    #pragma unroll
    for (int i = 0; i < 4; i++)
        #pragma unroll
        for (int j = 0; j < 4; j++) acc[i][j] = (floatx4)0.f;

    for (int k0 = 0; k0 < D_; k0 += 32) {
        #pragma unroll
        for (int j = 0; j < 2; j++) {
            int c = tid + j * 256;
            g2l16(Ap + (size_t)(c >> 2) * D_ + k0 + (c & 3) * 8, As + c * 8);
            g2l16(Bp + (size_t)(c >> 2) * D_ + k0 + (c & 3) * 8, Bs + c * 8);
        }
        __syncthreads();
        bf16x8 af[4], bfr[4];
        #pragma unroll
        for (int i = 0; i < 4; i++)
            af[i] = *(const bf16x8*)(As + (wm + i * 16 + ln15) * 32 + quad * 8);
        #pragma unroll
        for (int i = 0; i < 4; i++)
            bfr[i] = *(const bf16x8*)(Bs + (wn + i * 16 + ln15) * 32 + quad * 8);
        #pragma unroll
        for (int i = 0; i < 4; i++)
            #pragma unroll
            for (int j = 0; j < 4; j++)
                acc[i][j] = __builtin_amdgcn_mfma_f32_16x16x32_bf16(af[i], bfr[j], acc[i][j], 0, 0, 0);
        __syncthreads();
    }
    #pragma unroll
    for (int ni = 0; ni < 4; ni++) {
        int n = n0 + wn + ni * 16 + ln15;
        int h = n >> 6, dk = n & 63;
        float bv = bias[n];
        #pragma unroll
        for (int mi = 0; mi < 4; mi++)
            #pragma unroll
            for (int r = 0; r < 4; r++) {
                int m = m0 + wm + mi * 16 + quad * 4 + r;
                int b = m >> 10, l = m & 1023;
                out[(((size_t)h * B_ + b) * L_ + l) * DK_ + dk] = f2bf(acc[mi][ni][r] + bv);
            }
    }
}

// ---------------------------------------------------------------------------
// MFMA GEMM: FC + bias + residual -> f32 out [8192][768]
// ---------------------------------------------------------------------------
__global__ __launch_bounds__(256) void gemm_fc(
    const unsigned short* __restrict__ Abf, const unsigned short* __restrict__ Bt,
    const float* __restrict__ bias, const float* __restrict__ resid,
    float* __restrict__ out)
{
    __shared__ __align__(16) __bf16 As[128 * 32];
    __shared__ __align__(16) __bf16 Bs[128 * 32];
    const int tid = threadIdx.x;
    const int f = blockIdx.x + 6 * blockIdx.y;
    const int xcd = f & 7, j5 = f >> 3;
    const int n0 = (j5 % 6) * 128;
    const int m0 = (xcd * 8 + j5 / 6) * 128;
    const int lane = tid & 63, wv = tid >> 6;
    const int quad = lane >> 4, ln15 = lane & 15;
    const int wm = (wv >> 1) * 64, wn = (wv & 1) * 64;
    const __bf16* Ap = (const __bf16*)Abf + (size_t)m0 * D_;
    const __bf16* Bp = (const __bf16*)Bt + (size_t)n0 * D_;
    floatx4 acc[4][4];
    #pragma unroll
    for (int i = 0; i < 4; i++)
        #pragma unroll
        for (int j = 0; j < 4; j++) acc[i][j] = (floatx4)0.f;

    for (int k0 = 0; k0 < D_; k0 += 32) {
        #pragma unroll
        for (int j = 0; j < 2; j++) {
            int c = tid + j * 256;
            g2l16(Ap + (size_t)(c >> 2) * D_ + k0 + (c & 3) * 8, As + c * 8);
            g2l16(Bp + (size_t)(c >> 2) * D_ + k0 + (c & 3) * 8, Bs + c * 8);
        }
        __syncthreads();
        bf16x8 af[4], bfr[4];
        #pragma unroll
        for (int i = 0; i < 4; i++)
            af[i] = *(const bf16x8*)(As + (wm + i * 16 + ln15) * 32 + quad * 8);
        #pragma unroll
        for (int i = 0; i < 4; i++)
            bfr[i] = *(const bf16x8*)(Bs + (wn + i * 16 + ln15) * 32 + quad * 8);
        #pragma unroll
        for (int i = 0; i < 4; i++)
            #pragma unroll
            for (int j = 0; j < 4; j++)
                acc[i][j] = __builtin_amdgcn_mfma_f32_16x16x32_bf16(af[i], bfr[j], acc[i][j], 0, 0, 0);
        __syncthreads();
    }
    #pragma unroll
    for (int ni = 0; ni < 4; ni++) {
        int n = n0 + wn + ni * 16 + ln15;
        float bv = bias[n];
        #pragma unroll
        for (int mi = 0; mi < 4; mi++)
            #pragma unroll
            for (int r = 0; r < 4; r++) {
                int m = m0 + wm + mi * 16 + quad * 4 + r;
                size_t off = (size_t)m * D_ + n;
                out[off] = acc[mi][ni][r] + bv + resid[off];
            }
    }
}

// ---------------------------------------------------------------------------
// fused_s: u = relu_clip(ploc . w_loc + b) * exp2(SSCALE * Q K^T), plus
// invZ = 1/sum_t u.  Block = (b, 32 l-rows), 12 waves, wave = one head.
// ploc tile staged once in LDS, shared by all 12 heads (the whole reason
// the h-loop lives in one block).  Q/K fragments direct from global (L2;
// b == id&7 pins each batch's K slice to one XCD's L2).
// ---------------------------------------------------------------------------
__global__ __launch_bounds__(768) void fused_s_kernel(
    const unsigned short* __restrict__ Qh, const unsigned short* __restrict__ Kh,
    const float* __restrict__ ploc, const float* __restrict__ w_loc,
    const float* __restrict__ b_loc,
    unsigned short* __restrict__ U, float* __restrict__ invZ)
{
    const int id = blockIdx.x;
    const int b = id & 7, l0 = (id >> 3) * 32;
    const int tid = threadIdx.x;
    const int h = tid >> 6, lane = tid & 63;
    const int quad = lane >> 4, ln15 = lane & 15;
    __shared__ __align__(16) float pl[32 * 320];   // [l][t*5+d], 40 KB, linear

    const float w0 = w_loc[0 * H_ + h], w1 = w_loc[1 * H_ + h],
                w2 = w_loc[2 * H_ + h], w3 = w_loc[3 * H_ + h],
                w4 = w_loc[4 * H_ + h], bh = b_loc[h];

    const __bf16* Qp = (const __bf16*)Qh + (((size_t)h * B_ + b) * L_ + l0) * DK_;
    const __bf16* Kp = (const __bf16*)Kh + (((size_t)h * B_ + b) * L_) * DK_;
    unsigned short* Ub = U + (((size_t)h * B_ + b) * L_ + l0) * VALID_;
    const float* plsrc = ploc + ((size_t)(b * L_ + l0) * L_) * SD_;

    // Q fragments for this wave's 32 rows, kept in registers
    bf16x8 af[2][2];
    #pragma unroll
    for (int mi = 0; mi < 2; mi++)
        #pragma unroll
        for (int kk = 0; kk < 2; kk++)
            af[mi][kk] = *(const bf16x8*)(Qp + (size_t)(mi * 16 + ln15) * DK_ + kk * 32 + quad * 8);

    float zp[2][4];
    #pragma unroll
    for (int mi = 0; mi < 2; mi++)
        #pragma unroll
        for (int r = 0; r < 4; r++) zp[mi][r] = 0.f;

    for (int t0 = 0; t0 < VALID_; t0 += 64) {
        __syncthreads();   // previous tile's readers done
        // stage ploc[l0..l0+32][t0..t0+64][5] -> LDS (linear, async)
        #pragma unroll
        for (int i = 0; i < 4; i++) {
            int jj = tid + i * 768;
            if (jj < 2560) {
                int l = jj / 80, off = (jj % 80) * 4;
                g2l16(plsrc + (size_t)l * L_ * SD_ + t0 * SD_ + off, pl + l * 320 + off);
            }
        }
        __syncthreads();   // staging complete (vmcnt drained by barrier)

        // S = Q K^T for this 32x64 tile (per head)
        floatx4 acc[2][4];
        #pragma unroll
        for (int mi = 0; mi < 2; mi++)
            #pragma unroll
            for (int ni = 0; ni < 4; ni++) acc[mi][ni] = (floatx4)0.f;
        bf16x8 bfr[4][2];
        #pragma unroll
        for (int ni = 0; ni < 4; ni++)
            #pragma unroll
            for (int kk = 0; kk < 2; kk++)
                bfr[ni][kk] = *(const bf16x8*)(Kp + (size_t)(t0 + ni * 16 + ln15) * DK_ + kk * 32 + quad * 8);
        #pragma unroll
        for (int kk = 0; kk < 2; kk++)
            #pragma unroll
            for (int mi = 0; mi < 2; mi++)
                #pragma unroll
                for (int ni = 0; ni < 4; ni++)
                    acc[mi][ni] = __builtin_amdgcn_mfma_f32_16x16x32_bf16(af[mi][kk], bfr[ni][kk], acc[mi][ni], 0, 0, 0);

        // u = c * exp2(SSCALE * s); accumulate Z; store u bf16
        #pragma unroll
        for (int ni = 0; ni < 4; ni++) {
            int t = ni * 16 + ln15;
            #pragma unroll
            for (int mi = 0; mi < 2; mi++)
                #pragma unroll
                for (int r = 0; r < 4; r++) {
                    int lrow = mi * 16 + quad * 4 + r;
                    const float* pp = pl + lrow * 320 + t * 5;
                    float c = bh + pp[0] * w0 + pp[1] * w1 + pp[2] * w2
                                 + pp[3] * w3 + pp[4] * w4;
                    c = fmaxf(c, 1e-6f);             // relu + clip in one
                    float u = c * exp2f(acc[mi][ni][r] * SSCALE_);
                    zp[mi][r] += u;
                    Ub[(size_t)lrow * VALID_ + t0 + t] = f2bf(u);
                }
        }
    }
    // reduce Z over the 16 t-lanes (ln15)
    #pragma unroll
    for (int m = 1; m < 16; m <<= 1)
        #pragma unroll
        for (int mi = 0; mi < 2; mi++)
            #pragma unroll
            for (int r = 0; r < 4; r++)
                zp[mi][r] += __shfl_xor(zp[mi][r], m, 64);
    if (ln15 == 0) {
        #pragma unroll
        for (int mi = 0; mi < 2; mi++)
            #pragma unroll
            for (int r = 0; r < 4; r++) {
                int lrow = mi * 16 + quad * 4 + r;
                invZ[((size_t)h * B_ + b) * L_ + l0 + lrow] = 1.f / zp[mi][r];
            }
    }
}

// ---------------------------------------------------------------------------
// MFMA PV on u: O[l][dk] = invZ[l] * sum_t u[l][t] Vt[dk][t].
// Each staged u tile is also rescaled and written to fused f32 (final p),
// plus the zeroed masked tail -- the fused write rides on LDS data we
// already have.  XCD swizzle keeps each hb's Vt slice in one L2.
// ---------------------------------------------------------------------------
__global__ __launch_bounds__(256) void gemm_pv(
    const unsigned short* __restrict__ P, const unsigned short* __restrict__ Vt,
    const float* __restrict__ invZ,
    unsigned short* __restrict__ attn, float* __restrict__ fused)
{
    __shared__ __align__(16) __bf16 As[128 * 32];
    __shared__ __align__(16) __bf16 Bs[64 * 32];
    __shared__ float zrow[128];
    const int tid = threadIdx.x;
    const int f = blockIdx.x + 8 * blockIdx.y;
    const int xcd = f & 7, j5 = f >> 3;            // j5 in [0,96)
    const int hb = xcd * 12 + (j5 % 12);
    const int m0 = (j5 / 12) * 128;
    const int h = hb >> 3, b = hb & 7;
    const int lane = tid & 63, wv = tid >> 6;
    const int quad = lane >> 4, ln15 = lane & 15;
    const int wm = (wv >> 1) * 64, wn = (wv & 1) * 32;
    const __bf16* Ap = (const __bf16*)P + (size_t)hb * L_ * VALID_ + (size_t)m0 * VALID_;
    const __bf16* Bp = (const __bf16*)Vt + (size_t)hb * DK_ * VALID_;
    float* fbase = fused + ((size_t)hb * L_ + m0) * L_;
    if (tid < 128) zrow[tid] = invZ[(size_t)hb * L_ + m0 + tid];
    floatx4 acc[4][2];
    #pragma unroll
    for (int i = 0; i < 4; i++)
        #pragma unroll
        for (int j = 0; j < 2; j++) acc[i][j] = (floatx4)0.f;

    for (int k0 = 0; k0 < VALID_; k0 += 32) {
        #pragma unroll
        for (int j = 0; j < 2; j++) {
            int c = tid + j * 256;
            g2l16(Ap + (size_t)(c >> 2) * VALID_ + k0 + (c & 3) * 8, As + c * 8);
        }
        {
            int c = tid;
            g2l16(Bp + (size_t)(c >> 2) * VALID_ + k0 + (c & 3) * 8, Bs + c * 8);
        }
        __syncthreads();
        // fused p write: the staged u tile, rescaled, as f32
        {
            int row = tid >> 1, half = tid & 1;
            const __bf16* src = As + row * 32 + half * 16;
            float iz = zrow[row];
            bf16x8 v0 = *(const bf16x8*)(src);
            bf16x8 v1 = *(const bf16x8*)(src + 8);
            float* dst = fbase + (size_t)row * L_ + k0 + half * 16;
            #pragma unroll
            for (int jj = 0; jj < 8; jj++) dst[jj] = (float)v0[jj] * iz;
            #pragma unroll
            for (int jj = 0; jj < 8; jj++) dst[8 + jj] = (float)v1[jj] * iz;
        }
        bf16x8 af[4], bfr[2];
        #pragma unroll
        for (int i = 0; i < 4; i++)
            af[i] = *(const bf16x8*)(As + (wm + i * 16 + ln15) * 32 + quad * 8);
        #pragma unroll
        for (int i = 0; i < 2; i++)
            bfr[i] = *(const bf16x8*)(Bs + (wn + i * 16 + ln15) * 32 + quad * 8);
        #pragma unroll
        for (int i = 0; i < 4; i++)
            #pragma unroll
            for (int j = 0; j < 2; j++)
                acc[i][j] = __builtin_amdgcn_mfma_f32_16x16x32_bf16(af[i], bfr[j], acc[i][j], 0, 0, 0);
        __syncthreads();
    }
    // zero the masked tail of fused (t in [768,1024))
    {
        float4 z4 = make_float4(0.f, 0.f, 0.f, 0.f);
        #pragma unroll
        for (int i = 0; i < 32; i++) {
            int idx = tid + i * 256;
            int row = idx >> 6, c = (idx & 63) * 4;
            *(float4*)(fbase + (size_t)row * L_ + VALID_ + c) = z4;
        }
    }
    #pragma unroll
    for (int ni = 0; ni < 2; ni++) {
        int dk = wn + ni * 16 + ln15;
        #pragma unroll
        for (int mi = 0; mi < 4; mi++)
            #pragma unroll
            for (int r = 0; r < 4; r++) {
                int mloc = wm + mi * 16 + quad * 4 + r;
                int m = m0 + mloc;
                attn[((size_t)b * L_ + m) * D_ + h * DK_ + dk] =
                    f2bf(acc[mi][ni][r] * zrow[mloc]);
            }
    }
}

// ---------------------------------------------------------------------------
// LayerNorm in-place
// ---------------------------------------------------------------------------
__global__ __launch_bounds__(256) void ln_kernel(
    float* __restrict__ x, const float* __restrict__ g, const float* __restrict__ bb)
{
    const int r = blockIdx.x, tid = threadIdx.x;
    float* row = x + (size_t)r * D_;
    float v0 = row[tid], v1 = row[tid + 256], v2 = row[tid + 512];
    float s = v0 + v1 + v2;
    float s2 = v0 * v0 + v1 * v1 + v2 * v2;
    #pragma unroll
    for (int off = 32; off > 0; off >>= 1) {
        s  += __shfl_down(s, off, 64);
        s2 += __shfl_down(s2, off, 64);
    }
    __shared__ float rs[4], rs2[4], mb[2];
    const int lane = tid & 63, wid = tid >> 6;
    if (lane == 0) { rs[wid] = s; rs2[wid] = s2; }
    __syncthreads();
    if (tid == 0) {
        float S = rs[0] + rs[1] + rs[2] + rs[3];
        float S2 = rs2[0] + rs2[1] + rs2[2] + rs2[3];
        float mean = S * (1.f / 768.f);
        float var = S2 * (1.f / 768.f) - mean * mean;
        mb[0] = mean; mb[1] = rsqrtf(var + 1e-5f);
    }
    __syncthreads();
    float mean = mb[0], rstd = mb[1];
    row[tid]       = (v0 - mean) * rstd * g[tid]       + bb[tid];
    row[tid + 256] = (v1 - mean) * rstd * g[tid + 256] + bb[tid + 256];
    row[tid + 512] = (v2 - mean) * rstd * g[tid + 512] + bb[tid + 512];
}

// ---------------------------------------------------------------------------
extern "C" void kernel_launch(void* const* d_in, const int* in_sizes, int n_in,
                              void* d_out, int out_size, void* d_ws, size_t ws_size,
                              hipStream_t stream)
{
    const float* q     = (const float*)d_in[0];
    const float* k     = (const float*)d_in[1];
    const float* v     = (const float*)d_in[2];
    const float* ploc  = (const float*)d_in[3];
    const float* w_q   = (const float*)d_in[5];
    const float* b_q   = (const float*)d_in[6];
    const float* w_k   = (const float*)d_in[7];
    const float* b_k   = (const float*)d_in[8];
    const float* w_v   = (const float*)d_in[9];
    const float* b_v   = (const float*)d_in[10];
    const float* w_fc  = (const float*)d_in[11];
    const float* b_fc  = (const float*)d_in[12];
    const float* w_loc = (const float*)d_in[13];
    const float* b_loc = (const float*)d_in[14];
    const float* ln_g  = (const float*)d_in[15];
    const float* ln_b  = (const float*)d_in[16];

    float* out   = (float*)d_out;                       // [B,L,D]
    float* fused = out + (size_t)B_ * L_ * D_;          // [H,B,L,L]

    constexpr size_t NHE = (size_t)H_ * B_ * L_ * DK_;  // 6291456
    constexpr size_t NVT = (size_t)H_ * B_ * DK_ * VALID_;  // 4718592
    constexpr size_t NW  = (size_t)D_ * D_;             // 589824
    constexpr size_t NP  = (size_t)H_ * B_ * L_ * VALID_;   // 75497472
    unsigned short* Qh   = (unsigned short*)d_ws;
    unsigned short* Kh   = Qh + NHE;
    unsigned short* Vh   = Kh + NHE;
    unsigned short* Vt   = Vh + NHE;
    unsigned short* Xq   = Vt + NVT;
    unsigned short* Xk   = Xq + NHE;
    unsigned short* Xv   = Xk + NHE;
    unsigned short* WqT  = Xv + NHE;
    unsigned short* WkT  = WqT + NW;
    unsigned short* WvT  = WkT + NW;
    unsigned short* WfcT = WvT + NW;
    unsigned short* Pb   = WfcT + NW;   // u bf16 [h][b][l][t<768]
    unsigned short* AObf = Pb + NP;
    float* Zb            = (float*)(AObf + NHE);  // invZ [h][b][l]

    // prep: bf16 casts + weight transposes (fused launches)
    cvt3_kernel<<<dim3(3072, 3), 256, 0, stream>>>(q, k, v, Xq, Xk, Xv);
    wt4_kernel<<<dim3(12, 12, 4), 256, 0, stream>>>(w_q, w_k, w_v, w_fc, WqT, WkT, WvT, WfcT);
    // projections (MFMA), all three in one launch
    gemm_proj3<<<dim3(6, 64, 3), 256, 0, stream>>>(
        Xq, Xk, Xv, WqT, WkT, WvT, b_q, b_k, b_v, Qh, Kh, Vh);
    vt_kernel<<<dim3(12, 96), 256, 0, stream>>>(Vh, Vt);
    // fused QK^T + loc-attn + exp: u bf16 + invZ
    fused_s_kernel<<<256, 768, 0, stream>>>(Qh, Kh, ploc, w_loc, b_loc, Pb, Zb);
    // PV (MFMA) + fused f32 p-write + tail zeroing
    gemm_pv<<<dim3(8, 96), 256, 0, stream>>>(Pb, Vt, Zb, AObf, fused);
    // FC + bias + residual
    gemm_fc<<<dim3(6, 64), 256, 0, stream>>>(AObf, WfcT, b_fc, q, out);
    // LayerNorm
    ln_kernel<<<dim3(B_ * L_), 256, 0, stream>>>(out, ln_g, ln_b);
}

// Round 4
// 877.877 us; speedup vs baseline: 1.0306x; 1.0306x over previous
//
#include <hip/hip_runtime.h>
#include <hip/hip_bf16.h>

// Problem constants
constexpr int B_  = 8;
constexpr int L_  = 1024;
constexpr int D_  = 768;
constexpr int H_  = 12;
constexpr int DK_ = 64;
constexpr int SD_ = 5;
constexpr int VALID_ = 768;   // keys t >= 768 are masked

// 0.125 (1/sqrt(64)) * log2(e): exp(0.125*s) = exp2(SSCALE*s)
constexpr float SSCALE_ = 0.18033688011112042f;

typedef __attribute__((ext_vector_type(8))) __bf16 bf16x8;
typedef __attribute__((ext_vector_type(4))) float floatx4;

__device__ __forceinline__ unsigned short f2bf(float f) {
    unsigned int u = __float_as_uint(f);
    unsigned int r = (u + 0x7FFFu + ((u >> 16) & 1u)) >> 16;  // RNE
    return (unsigned short)r;
}

__device__ __forceinline__ float bf2f(unsigned short us) {
    return __uint_as_float((unsigned int)us << 16);
}

// async global->LDS, 16B per lane. LDS dest must be linear in lane id.
__device__ __forceinline__ void g2l16(const void* g, void* l) {
    __builtin_amdgcn_global_load_lds(
        (const __attribute__((address_space(1))) void*)g,
        (__attribute__((address_space(3))) void*)l, 16, 0, 0);
}

// ---------------------------------------------------------------------------
// f32 -> bf16 elementwise (8 elems/thread), 3 tensors in one launch
// ---------------------------------------------------------------------------
__global__ __launch_bounds__(256) void cvt3_kernel(
    const float* __restrict__ x0, const float* __restrict__ x1,
    const float* __restrict__ x2,
    unsigned short* __restrict__ o0, unsigned short* __restrict__ o1,
    unsigned short* __restrict__ o2)
{
    const int w = blockIdx.y;
    const float* x = (w == 0) ? x0 : (w == 1) ? x1 : x2;
    unsigned short* o = (w == 0) ? o0 : (w == 1) ? o1 : o2;
    size_t i = ((size_t)blockIdx.x * 256 + threadIdx.x) * 8;
    float4 a = *(const float4*)(x + i);
    float4 b = *(const float4*)(x + i + 4);
    ushort4 q1; q1.x = f2bf(a.x); q1.y = f2bf(a.y); q1.z = f2bf(a.z); q1.w = f2bf(a.w);
    ushort4 q2; q2.x = f2bf(b.x); q2.y = f2bf(b.y); q2.z = f2bf(b.z); q2.w = f2bf(b.w);
    *(ushort4*)(o + i) = q1;
    *(ushort4*)(o + i + 4) = q2;
}

// ---------------------------------------------------------------------------
// W [768k][768n] f32 -> Wt [n][k] bf16 (transpose + convert), 64x64 tiles
// 4 weight matrices in one launch (blockIdx.z)
// ---------------------------------------------------------------------------
__global__ __launch_bounds__(256) void wt4_kernel(
    const float* __restrict__ W0, const float* __restrict__ W1,
    const float* __restrict__ W2, const float* __restrict__ W3,
    unsigned short* __restrict__ T0, unsigned short* __restrict__ T1,
    unsigned short* __restrict__ T2, unsigned short* __restrict__ T3)
{
    const int w = blockIdx.z;
    const float* W = (w == 0) ? W0 : (w == 1) ? W1 : (w == 2) ? W2 : W3;
    unsigned short* Wt = (w == 0) ? T0 : (w == 1) ? T1 : (w == 2) ? T2 : T3;
    __shared__ float tl[64][65];
    const int k0 = blockIdx.x * 64, n0 = blockIdx.y * 64;
    const int tid = threadIdx.x;
    #pragma unroll
    for (int i = 0; i < 4; i++) {
        int c = tid + i * 256;
        int r = c >> 4, c4 = (c & 15) * 4;
        float4 v = *(const float4*)(W + (size_t)(k0 + r) * D_ + n0 + c4);
        tl[r][c4] = v.x; tl[r][c4 + 1] = v.y; tl[r][c4 + 2] = v.z; tl[r][c4 + 3] = v.w;
    }
    __syncthreads();
    #pragma unroll
    for (int i = 0; i < 4; i++) {
        int c = tid + i * 256;
        int n_ = c >> 4, k4 = (c & 15) * 4;
        ushort4 o;
        o.x = f2bf(tl[k4 + 0][n_]); o.y = f2bf(tl[k4 + 1][n_]);
        o.z = f2bf(tl[k4 + 2][n_]); o.w = f2bf(tl[k4 + 3][n_]);
        *(ushort4*)(Wt + (size_t)(n0 + n_) * D_ + k0 + k4) = o;
    }
}

// ---------------------------------------------------------------------------
// Vh [hb][t][dk] bf16 -> Vt [hb][dk][t<768] bf16
// ---------------------------------------------------------------------------
__global__ __launch_bounds__(256) void vt_kernel(
    const unsigned short* __restrict__ Vh, unsigned short* __restrict__ Vt)
{
    __shared__ unsigned short tl[64][65];
    const int t0 = blockIdx.x * 64, hb = blockIdx.y;
    const int tid = threadIdx.x;
    const unsigned short* src = Vh + (size_t)hb * L_ * DK_ + (size_t)t0 * DK_;
    #pragma unroll
    for (int i = 0; i < 4; i++) {
        int c = tid + i * 256;
        int r = c >> 4, c4 = (c & 15) * 4;
        ushort4 v = *(const ushort4*)(src + r * DK_ + c4);
        tl[r][c4] = v.x; tl[r][c4 + 1] = v.y; tl[r][c4 + 2] = v.z; tl[r][c4 + 3] = v.w;
    }
    __syncthreads();
    unsigned short* dst = Vt + (size_t)hb * DK_ * VALID_ + t0;
    #pragma unroll
    for (int i = 0; i < 4; i++) {
        int c = tid + i * 256;
        int dk = c >> 4, t4 = (c & 15) * 4;
        ushort4 o;
        o.x = tl[t4 + 0][dk]; o.y = tl[t4 + 1][dk];
        o.z = tl[t4 + 2][dk]; o.w = tl[t4 + 3][dk];
        *(ushort4*)(dst + (size_t)dk * VALID_ + t4) = o;
    }
}

// ---------------------------------------------------------------------------
// MFMA GEMM, 128x128 tile, BK=32: out bf16 head-major [h][b][l][dk], +bias
// XCD-pinned m-panels: the 6 n-tile blocks of one A-panel share one XCD L2.
// ---------------------------------------------------------------------------
__global__ __launch_bounds__(256) void gemm_proj3(
    const unsigned short* __restrict__ A0, const unsigned short* __restrict__ A1,
    const unsigned short* __restrict__ A2,
    const unsigned short* __restrict__ B0, const unsigned short* __restrict__ B1,
    const unsigned short* __restrict__ B2,
    const float* __restrict__ bias0, const float* __restrict__ bias1,
    const float* __restrict__ bias2,
    unsigned short* __restrict__ O0, unsigned short* __restrict__ O1,
    unsigned short* __restrict__ O2)
{
    const int which = blockIdx.z;
    const unsigned short* Abf = (which == 0) ? A0 : (which == 1) ? A1 : A2;
    const unsigned short* Bt  = (which == 0) ? B0 : (which == 1) ? B1 : B2;
    const float* bias         = (which == 0) ? bias0 : (which == 1) ? bias1 : bias2;
    unsigned short* out       = (which == 0) ? O0 : (which == 1) ? O1 : O2;

    __shared__ __align__(16) __bf16 As[128 * 32];
    __shared__ __align__(16) __bf16 Bs[128 * 32];
    const int tid = threadIdx.x;
    // XCD swizzle: f%8 ~ XCD; each XCD owns 8 consecutive m-panels
    const int f = blockIdx.x + 6 * blockIdx.y;
    const int xcd = f & 7, j5 = f >> 3;            // j5 in [0,48)
    const int n0 = (j5 % 6) * 128;
    const int m0 = (xcd * 8 + j5 / 6) * 128;
    const int lane = tid & 63, wv = tid >> 6;
    const int quad = lane >> 4, ln15 = lane & 15;
    const int wm = (wv >> 1) * 64, wn = (wv & 1) * 64;
    const __bf16* Ap = (const __bf16*)Abf + (size_t)m0 * D_;
    const __bf16* Bp = (const __bf16*)Bt + (size_t)n0 * D_;
    floatx4 acc[4][4];
    #pragma unroll
    for (int i = 0; i < 4; i++)
        #pragma unroll
        for (int j = 0; j < 4; j++) acc[i][j] = (floatx4)0.f;

    for (int k0 = 0; k0 < D_; k0 += 32) {
        #pragma unroll
        for (int j = 0; j < 2; j++) {
            int c = tid + j * 256;
            g2l16(Ap + (size_t)(c >> 2) * D_ + k0 + (c & 3) * 8, As + c * 8);
            g2l16(Bp + (size_t)(c >> 2) * D_ + k0 + (c & 3) * 8, Bs + c * 8);
        }
        __syncthreads();
        bf16x8 af[4], bfr[4];
        #pragma unroll
        for (int i = 0; i < 4; i++)
            af[i] = *(const bf16x8*)(As + (wm + i * 16 + ln15) * 32 + quad * 8);
        #pragma unroll
        for (int i = 0; i < 4; i++)
            bfr[i] = *(const bf16x8*)(Bs + (wn + i * 16 + ln15) * 32 + quad * 8);
        #pragma unroll
        for (int i = 0; i < 4; i++)
            #pragma unroll
            for (int j = 0; j < 4; j++)
                acc[i][j] = __builtin_amdgcn_mfma_f32_16x16x32_bf16(af[i], bfr[j], acc[i][j], 0, 0, 0);
        __syncthreads();
    }
    #pragma unroll
    for (int ni = 0; ni < 4; ni++) {
        int n = n0 + wn + ni * 16 + ln15;
        int h = n >> 6, dk = n & 63;
        float bv = bias[n];
        #pragma unroll
        for (int mi = 0; mi < 4; mi++)
            #pragma unroll
            for (int r = 0; r < 4; r++) {
                int m = m0 + wm + mi * 16 + quad * 4 + r;
                int b = m >> 10, l = m & 1023;
                out[(((size_t)h * B_ + b) * L_ + l) * DK_ + dk] = f2bf(acc[mi][ni][r] + bv);
            }
    }
}

// ---------------------------------------------------------------------------
// MFMA GEMM: FC + bias + residual -> f32 out [8192][768], XCD-pinned panels
// ---------------------------------------------------------------------------
__global__ __launch_bounds__(256) void gemm_fc(
    const unsigned short* __restrict__ Abf, const unsigned short* __restrict__ Bt,
    const float* __restrict__ bias, const float* __restrict__ resid,
    float* __restrict__ out)
{
    __shared__ __align__(16) __bf16 As[128 * 32];
    __shared__ __align__(16) __bf16 Bs[128 * 32];
    const int tid = threadIdx.x;
    const int f = blockIdx.x + 6 * blockIdx.y;
    const int xcd = f & 7, j5 = f >> 3;
    const int n0 = (j5 % 6) * 128;
    const int m0 = (xcd * 8 + j5 / 6) * 128;
    const int lane = tid & 63, wv = tid >> 6;
    const int quad = lane >> 4, ln15 = lane & 15;
    const int wm = (wv >> 1) * 64, wn = (wv & 1) * 64;
    const __bf16* Ap = (const __bf16*)Abf + (size_t)m0 * D_;
    const __bf16* Bp = (const __bf16*)Bt + (size_t)n0 * D_;
    floatx4 acc[4][4];
    #pragma unroll
    for (int i = 0; i < 4; i++)
        #pragma unroll
        for (int j = 0; j < 4; j++) acc[i][j] = (floatx4)0.f;

    for (int k0 = 0; k0 < D_; k0 += 32) {
        #pragma unroll
        for (int j = 0; j < 2; j++) {
            int c = tid + j * 256;
            g2l16(Ap + (size_t)(c >> 2) * D_ + k0 + (c & 3) * 8, As + c * 8);
            g2l16(Bp + (size_t)(c >> 2) * D_ + k0 + (c & 3) * 8, Bs + c * 8);
        }
        __syncthreads();
        bf16x8 af[4], bfr[4];
        #pragma unroll
        for (int i = 0; i < 4; i++)
            af[i] = *(const bf16x8*)(As + (wm + i * 16 + ln15) * 32 + quad * 8);
        #pragma unroll
        for (int i = 0; i < 4; i++)
            bfr[i] = *(const bf16x8*)(Bs + (wn + i * 16 + ln15) * 32 + quad * 8);
        #pragma unroll
        for (int i = 0; i < 4; i++)
            #pragma unroll
            for (int j = 0; j < 4; j++)
                acc[i][j] = __builtin_amdgcn_mfma_f32_16x16x32_bf16(af[i], bfr[j], acc[i][j], 0, 0, 0);
        __syncthreads();
    }
    #pragma unroll
    for (int ni = 0; ni < 4; ni++) {
        int n = n0 + wn + ni * 16 + ln15;
        float bv = bias[n];
        #pragma unroll
        for (int mi = 0; mi < 4; mi++)
            #pragma unroll
            for (int r = 0; r < 4; r++) {
                int m = m0 + wm + mi * 16 + quad * 4 + r;
                size_t off = (size_t)m * D_ + n;
                out[off] = acc[mi][ni][r] + bv + resid[off];
            }
    }
}

// ---------------------------------------------------------------------------
// MFMA S~ = (0.125*log2e) * Q K^T per hb, written bf16 into Pb.
// M=1024 (l), N=768 valid (t), K=64.  No LDS: Q/K tiles are L2-resident.
// ---------------------------------------------------------------------------
__global__ __launch_bounds__(256) void gemm_s(
    const unsigned short* __restrict__ Qh, const unsigned short* __restrict__ Kh,
    unsigned short* __restrict__ Sb)
{
    const int tid = threadIdx.x;
    const int n0 = blockIdx.x * 128, m0 = blockIdx.y * 128, hb = blockIdx.z;
    const int lane = tid & 63, wv = tid >> 6;
    const int quad = lane >> 4, ln15 = lane & 15;
    const int wm = (wv >> 1) * 64, wn = (wv & 1) * 64;
    const __bf16* Aq = (const __bf16*)Qh + (size_t)hb * L_ * DK_;
    const __bf16* Bk = (const __bf16*)Kh + (size_t)hb * L_ * DK_;
    floatx4 acc[4][4];
    #pragma unroll
    for (int i = 0; i < 4; i++)
        #pragma unroll
        for (int j = 0; j < 4; j++) acc[i][j] = (floatx4)0.f;

    #pragma unroll
    for (int kk = 0; kk < 2; kk++) {
        bf16x8 af[4], bfr[4];
        #pragma unroll
        for (int i = 0; i < 4; i++)
            af[i] = *(const bf16x8*)(Aq + (size_t)(m0 + wm + i * 16 + ln15) * DK_ + kk * 32 + quad * 8);
        #pragma unroll
        for (int i = 0; i < 4; i++)
            bfr[i] = *(const bf16x8*)(Bk + (size_t)(n0 + wn + i * 16 + ln15) * DK_ + kk * 32 + quad * 8);
        #pragma unroll
        for (int i = 0; i < 4; i++)
            #pragma unroll
            for (int j = 0; j < 4; j++)
                acc[i][j] = __builtin_amdgcn_mfma_f32_16x16x32_bf16(af[i], bfr[j], acc[i][j], 0, 0, 0);
    }
    unsigned short* So = Sb + (size_t)hb * L_ * VALID_;
    #pragma unroll
    for (int ni = 0; ni < 4; ni++) {
        int n = n0 + wn + ni * 16 + ln15;
        #pragma unroll
        for (int mi = 0; mi < 4; mi++)
            #pragma unroll
            for (int r = 0; r < 4; r++) {
                int m = m0 + wm + mi * 16 + quad * 4 + r;
                So[(size_t)m * VALID_ + n] = f2bf(acc[mi][ni][r] * SSCALE_);
            }
    }
}

// ---------------------------------------------------------------------------
// fused loc-attn + softmax: p = c*exp2(s~)/Z.  Reads s~ bf16 from Pb,
// overwrites Pb IN PLACE with p bf16, writes final p f32 to fused
// (incl. zeroed tail).  One block per (b,l).
// ---------------------------------------------------------------------------
__global__ __launch_bounds__(256) void softmax_loc_kernel(
    const float* __restrict__ ploc, const float* __restrict__ w_loc,
    const float* __restrict__ b_loc, float* __restrict__ fused,
    unsigned short* __restrict__ pb)
{
    const int bl = blockIdx.x;
    const int b = bl >> 10, l = bl & 1023;
    const int tid = threadIdx.x;
    __shared__ float red[H_][4];
    __shared__ float invZ[H_];

    // uniform reads -> scalar loads (SGPRs), no LDS round-trip
    float wl0[H_], wl1[H_], wl2[H_], wl3[H_], wl4[H_], blh[H_];
    #pragma unroll
    for (int h = 0; h < H_; h++) {
        wl0[h] = w_loc[0 * H_ + h];
        wl1[h] = w_loc[1 * H_ + h];
        wl2[h] = w_loc[2 * H_ + h];
        wl3[h] = w_loc[3 * H_ + h];
        wl4[h] = w_loc[4 * H_ + h];
        blh[h] = b_loc[h];
    }

    float u[3][H_];
    float zp[H_];
    #pragma unroll
    for (int h = 0; h < H_; h++) zp[h] = 0.f;

    #pragma unroll
    for (int it = 0; it < 3; it++) {
        int t = tid + it * 256;
        const float* lp = ploc + ((size_t)bl * L_ + t) * SD_;
        float d0 = lp[0], d1 = lp[1], d2 = lp[2], d3 = lp[3], d4 = lp[4];
        #pragma unroll
        for (int h = 0; h < H_; h++) {
            float v = blh[h] + d0 * wl0[h] + d1 * wl1[h] + d2 * wl2[h]
                            + d3 * wl3[h] + d4 * wl4[h];
            v = fmaxf(v, 1e-6f);   // relu + clip in one
            float s = bf2f(pb[(((size_t)h * B_ + b) * L_ + l) * VALID_ + t]);
            float uu = v * exp2f(s);
            u[it][h] = uu;
            zp[h] += uu;
        }
    }
    const int lane = tid & 63, wid = tid >> 6;
    #pragma unroll
    for (int h = 0; h < H_; h++) {
        float z = zp[h];
        #pragma unroll
        for (int off = 32; off > 0; off >>= 1) z += __shfl_down(z, off, 64);
        if (lane == 0) red[h][wid] = z;
    }
    __syncthreads();
    if (tid < H_) invZ[tid] = 1.f / (red[tid][0] + red[tid][1] + red[tid][2] + red[tid][3]);
    __syncthreads();
    #pragma unroll
    for (int it = 0; it < 3; it++) {
        int t = tid + it * 256;
        #pragma unroll
        for (int h = 0; h < H_; h++) {
            float p = u[it][h] * invZ[h];
            fused[(((size_t)h * B_ + b) * L_ + l) * L_ + t] = p;
            pb[(((size_t)h * B_ + b) * L_ + l) * VALID_ + t] = f2bf(p);
        }
    }
    int t = VALID_ + tid;
    #pragma unroll
    for (int h = 0; h < H_; h++)
        fused[(((size_t)h * B_ + b) * L_ + l) * L_ + t] = 0.f;
}

// ---------------------------------------------------------------------------
// MFMA PV: O[l][dk] = sum_t P[l][t] Vt[dk][t]; out bf16 [b][l][h*64+dk]
// BM=128, BN=64, K=768; XCD-pinned hb: all 8 m-tiles of one hb share an XCD.
// ---------------------------------------------------------------------------
__global__ __launch_bounds__(256) void gemm_pv(
    const unsigned short* __restrict__ P, const unsigned short* __restrict__ Vt,
    unsigned short* __restrict__ attn)
{
    __shared__ __align__(16) __bf16 As[128 * 32];
    __shared__ __align__(16) __bf16 Bs[64 * 32];
    const int tid = threadIdx.x;
    const int f = blockIdx.x + 8 * blockIdx.y;
    const int xcd = f & 7, j5 = f >> 3;            // j5 in [0,96)
    const int hb = xcd * 12 + (j5 % 12);
    const int m0 = (j5 / 12) * 128;
    const int h = hb >> 3, b = hb & 7;
    const int lane = tid & 63, wv = tid >> 6;
    const int quad = lane >> 4, ln15 = lane & 15;
    const int wm = (wv >> 1) * 64, wn = (wv & 1) * 32;
    const __bf16* Ap = (const __bf16*)P + (size_t)hb * L_ * VALID_ + (size_t)m0 * VALID_;
    const __bf16* Bp = (const __bf16*)Vt + (size_t)hb * DK_ * VALID_;
    floatx4 acc[4][2];
    #pragma unroll
    for (int i = 0; i < 4; i++)
        #pragma unroll
        for (int j = 0; j < 2; j++) acc[i][j] = (floatx4)0.f;

    for (int k0 = 0; k0 < VALID_; k0 += 32) {
        #pragma unroll
        for (int j = 0; j < 2; j++) {
            int c = tid + j * 256;
            g2l16(Ap + (size_t)(c >> 2) * VALID_ + k0 + (c & 3) * 8, As + c * 8);
        }
        {
            int c = tid;
            g2l16(Bp + (size_t)(c >> 2) * VALID_ + k0 + (c & 3) * 8, Bs + c * 8);
        }
        __syncthreads();
        bf16x8 af[4], bfr[2];
        #pragma unroll
        for (int i = 0; i < 4; i++)
            af[i] = *(const bf16x8*)(As + (wm + i * 16 + ln15) * 32 + quad * 8);
        #pragma unroll
        for (int i = 0; i < 2; i++)
            bfr[i] = *(const bf16x8*)(Bs + (wn + i * 16 + ln15) * 32 + quad * 8);
        #pragma unroll
        for (int i = 0; i < 4; i++)
            #pragma unroll
            for (int j = 0; j < 2; j++)
                acc[i][j] = __builtin_amdgcn_mfma_f32_16x16x32_bf16(af[i], bfr[j], acc[i][j], 0, 0, 0);
        __syncthreads();
    }
    #pragma unroll
    for (int ni = 0; ni < 2; ni++) {
        int dk = wn + ni * 16 + ln15;
        #pragma unroll
        for (int mi = 0; mi < 4; mi++)
            #pragma unroll
            for (int r = 0; r < 4; r++) {
                int m = m0 + wm + mi * 16 + quad * 4 + r;
                attn[((size_t)b * L_ + m) * D_ + h * DK_ + dk] = f2bf(acc[mi][ni][r]);
            }
    }
}

// ---------------------------------------------------------------------------
// LayerNorm in-place
// ---------------------------------------------------------------------------
__global__ __launch_bounds__(256) void ln_kernel(
    float* __restrict__ x, const float* __restrict__ g, const float* __restrict__ bb)
{
    const int r = blockIdx.x, tid = threadIdx.x;
    float* row = x + (size_t)r * D_;
    float v0 = row[tid], v1 = row[tid + 256], v2 = row[tid + 512];
    float s = v0 + v1 + v2;
    float s2 = v0 * v0 + v1 * v1 + v2 * v2;
    #pragma unroll
    for (int off = 32; off > 0; off >>= 1) {
        s  += __shfl_down(s, off, 64);
        s2 += __shfl_down(s2, off, 64);
    }
    __shared__ float rs[4], rs2[4], mb[2];
    const int lane = tid & 63, wid = tid >> 6;
    if (lane == 0) { rs[wid] = s; rs2[wid] = s2; }
    __syncthreads();
    if (tid == 0) {
        float S = rs[0] + rs[1] + rs[2] + rs[3];
        float S2 = rs2[0] + rs2[1] + rs2[2] + rs2[3];
        float mean = S * (1.f / 768.f);
        float var = S2 * (1.f / 768.f) - mean * mean;
        mb[0] = mean; mb[1] = rsqrtf(var + 1e-5f);
    }
    __syncthreads();
    float mean = mb[0], rstd = mb[1];
    row[tid]       = (v0 - mean) * rstd * g[tid]       + bb[tid];
    row[tid + 256] = (v1 - mean) * rstd * g[tid + 256] + bb[tid + 256];
    row[tid + 512] = (v2 - mean) * rstd * g[tid + 512] + bb[tid + 512];
}

// ---------------------------------------------------------------------------
extern "C" void kernel_launch(void* const* d_in, const int* in_sizes, int n_in,
                              void* d_out, int out_size, void* d_ws, size_t ws_size,
                              hipStream_t stream)
{
    const float* q     = (const float*)d_in[0];
    const float* k     = (const float*)d_in[1];
    const float* v     = (const float*)d_in[2];
    const float* ploc  = (const float*)d_in[3];
    const float* w_q   = (const float*)d_in[5];
    const float* b_q   = (const float*)d_in[6];
    const float* w_k   = (const float*)d_in[7];
    const float* b_k   = (const float*)d_in[8];
    const float* w_v   = (const float*)d_in[9];
    const float* b_v   = (const float*)d_in[10];
    const float* w_fc  = (const float*)d_in[11];
    const float* b_fc  = (const float*)d_in[12];
    const float* w_loc = (const float*)d_in[13];
    const float* b_loc = (const float*)d_in[14];
    const float* ln_g  = (const float*)d_in[15];
    const float* ln_b  = (const float*)d_in[16];

    float* out   = (float*)d_out;                       // [B,L,D]
    float* fused = out + (size_t)B_ * L_ * D_;          // [H,B,L,L]

    constexpr size_t NHE = (size_t)H_ * B_ * L_ * DK_;  // 6291456
    constexpr size_t NVT = (size_t)H_ * B_ * DK_ * VALID_;  // 4718592
    constexpr size_t NW  = (size_t)D_ * D_;             // 589824
    constexpr size_t NP  = (size_t)H_ * B_ * L_ * VALID_;   // 75497472
    unsigned short* Qh   = (unsigned short*)d_ws;
    unsigned short* Kh   = Qh + NHE;
    unsigned short* Vh   = Kh + NHE;
    unsigned short* Vt   = Vh + NHE;
    unsigned short* Xq   = Vt + NVT;
    unsigned short* Xk   = Xq + NHE;
    unsigned short* Xv   = Xk + NHE;
    unsigned short* WqT  = Xv + NHE;
    unsigned short* WkT  = WqT + NW;
    unsigned short* WvT  = WkT + NW;
    unsigned short* WfcT = WvT + NW;
    unsigned short* Pb   = WfcT + NW;   // holds s~ bf16, then p bf16 in place
    unsigned short* AObf = Pb + NP;

    // prep: bf16 casts + weight transposes (fused launches)
    cvt3_kernel<<<dim3(3072, 3), 256, 0, stream>>>(q, k, v, Xq, Xk, Xv);
    wt4_kernel<<<dim3(12, 12, 4), 256, 0, stream>>>(w_q, w_k, w_v, w_fc, WqT, WkT, WvT, WfcT);
    // projections (MFMA), all three in one launch
    gemm_proj3<<<dim3(6, 64, 3), 256, 0, stream>>>(
        Xq, Xk, Xv, WqT, WkT, WvT, b_q, b_k, b_v, Qh, Kh, Vh);
    vt_kernel<<<dim3(12, 96), 256, 0, stream>>>(Vh, Vt);
    // s~ = (0.125*log2e) * Q K^T -> bf16 into Pb (valid t only)
    gemm_s<<<dim3(6, 8, 96), 256, 0, stream>>>(Qh, Kh, Pb);
    // fused loc-attn + softmax (reads s~ from Pb, writes p f32 + p bf16 in place)
    softmax_loc_kernel<<<dim3(B_ * L_), 256, 0, stream>>>(ploc, w_loc, b_loc, fused, Pb);
    // PV (MFMA)
    gemm_pv<<<dim3(8, 96), 256, 0, stream>>>(Pb, Vt, AObf);
    // FC + bias + residual
    gemm_fc<<<dim3(6, 64), 256, 0, stream>>>(AObf, WfcT, b_fc, q, out);
    // LayerNorm
    ln_kernel<<<dim3(B_ * L_), 256, 0, stream>>>(out, ln_g, ln_b);
}